// Round 9
// baseline (276.331 us; speedup 1.0000x reference)
//
#include <hip/hip_runtime.h>

#define STEPS 100
#define BATCH 256
#define D1 784
#define D1P 785            // +1 zero row = padding target for gathers
#define D2 512
#define NSTEP 99           // computed steps t = 0..98 (output rows 1..99)
#define NTB (NSTEP * BATCH)        // 25344
#define LIST_PAD 80        // u16 entries per (t,b); max spikes ~66 (verified R3+)
#define ROWB 48            // LDS row stride in bytes (8-col slice, 12 floats)
#define NBLK_T 400         // fused-prep transpose blocks

// ---- tier-1 (hybrid) ws layout: Wt fp32 ++ lists u16(raw idx) ++ cnt8 ++ z --
#define WT_BYTES   (D1P * D2 * 4)                            // 1,607,680
#define H_LISTS_OFF ((size_t)WT_BYTES)
#define H_LISTS_BYTES ((size_t)NTB * LIST_PAD * 2)           // 4,055,040
#define H_CNTS_OFF (H_LISTS_OFF + H_LISTS_BYTES)
#define H_CNTS_BYTES ((size_t)NTB * 4)
#define H_Z_OFF    (((H_CNTS_OFF + H_CNTS_BYTES) + 255) & ~(size_t)255)
#define Z_BYTES    ((size_t)NTB * D2 * 4)                    // 51,904,512
#define WS_T1      (H_Z_OFF + Z_BYTES)                       // ~57.7 MB

// ---- tier-2 (R8 pure-LDS) ws layout: lists u16(i*48) ++ cnt4 ++ z ----
#define L2_LISTS_OFF 0
#define L2_CNTS_OFF  ((size_t)NTB * LIST_PAD * 2)
#define L2_Z_OFF     (((L2_CNTS_OFF + (size_t)NTB * 4) + 255) & ~(size_t)255)
#define WS_T2        (L2_Z_OFF + Z_BYTES)                    // ~56.1 MB

// ---- tier-3 (R6) ws layout: Wt fp32 ++ z ----
#define T3_Z_OFF  ((size_t)((WT_BYTES + 255) & ~255))
#define WS_T3     (T3_Z_OFF + Z_BYTES)                       // ~53.5 MB

#define HALF1 392
#define HCAP  64

// ======================= tier-1 kernels ======================================

// fused prep: blocks [0,400) transpose W -> Wt [D1P][D2] (row 784 zeroed);
// blocks [400,..): one wave per (t,b), emit RAW u16 indices padded to a
// multiple of 8 with the zero-row index 784.
__global__ __launch_bounds__(256) void prep_fused(
    const float* __restrict__ W, const float* __restrict__ x,
    float* __restrict__ Wt, unsigned short* __restrict__ lists,
    unsigned int* __restrict__ cnt8s)
{
    if (blockIdx.x < NBLK_T) {
        __shared__ float tile[32][33];
        int bt = blockIdx.x;
        int i0 = (bt % 25) * 32;
        int j0 = (bt / 25) * 32;
        int tx = threadIdx.x & 31, ty = threadIdx.x >> 5;
        for (int r = 0; r < 32; r += 8) {
            int jj = j0 + ty + r, ii = i0 + tx;
            float v = 0.f;
            if (jj < D2 && ii < D1) v = W[jj * D1 + ii];
            tile[ty + r][tx] = v;
        }
        __syncthreads();
        for (int r = 0; r < 32; r += 8) {
            int ii = i0 + ty + r, jj = j0 + tx;
            if (ii < D1P && jj < D2) Wt[ii * D2 + jj] = tile[tx][ty + r];
        }
        return;
    }
    const int wid  = (blockIdx.x - NBLK_T) * 4 + (threadIdx.x >> 6); // t*BATCH+b
    const int lane = threadIdx.x & 63;
    const float* xt = x + (size_t)wid * D1;
    unsigned short* lp = lists + (size_t)wid * LIST_PAD;

    int cnt = 0;
    for (int base = 0; base < D1; base += 64) {
        int i = base + lane;
        bool a = (i < D1) && (xt[i] > 0.5f);
        unsigned long long m = __ballot(a);
        int pre = __popcll(m & ((1ull << lane) - 1ull));
        if (a) {
            int p = cnt + pre;
            if (p < LIST_PAD) lp[p] = (unsigned short)i;
        }
        cnt += __popcll(m);
    }
    if (cnt > LIST_PAD) cnt = LIST_PAD;
    int cnt8 = (cnt + 7) & ~7;
    if (lane < cnt8 - cnt) lp[cnt + lane] = (unsigned short)D1;  // zero row
    if (lane == 0) cnt8s[wid] = (unsigned int)cnt8;
}

// hybrid gather: blocks [0,512) = LDS-role (8-col slices, j 0..255);
// blocks [512,768) = global-role (16-col slices, j 256..511, full-line reads).
// Both pipes (LDS + vector-memory) run concurrently on each CU.
__global__ __launch_bounds__(256, 3) void gather_hybrid(
    const float* __restrict__ Wtg,             // [D1P][D2]
    const unsigned short* __restrict__ lists,  // raw u16 indices
    const unsigned int* __restrict__ cnt8s,    // multiples of 8
    float* __restrict__ z)                     // [NSTEP][BATCH][D2]
{
    __shared__ __align__(16) float wt[D1P * (ROWB / 4)];   // 37,680 B

    if (blockIdx.x < 512) {
        // ---------------- LDS-role ----------------
        const int slice = blockIdx.x & 31;     // j-slice of 8 in [0,256)
        const int chunk = blockIdx.x >> 5;     // 16 chunks of 1584 tbs
        const int j0 = slice * 8;

        for (int v = threadIdx.x; v < 8 * D1P; v += 256) {
            int jj = v & 7;
            int i  = v >> 3;
            wt[i * (ROWB / 4) + jj] = Wtg[(size_t)i * D2 + j0 + jj];
        }
        __syncthreads();

        const int tbsub = threadIdx.x >> 1;                       // 0..127
        const unsigned int jb = (unsigned int)((threadIdx.x & 1) << 4);
        const char* base = (const char*)wt;
        const int tb0 = chunk * (NTB / 16);
        const int tb1 = tb0 + (NTB / 16);

        for (int tb = tb0 + tbsub; tb < tb1; tb += 128) {
            const unsigned short* lp = lists + (size_t)tb * LIST_PAD;
            const int c8 = (int)cnt8s[tb];
            float ax = 0.f, ay = 0.f, az = 0.f, aw = 0.f;
            float bx = 0.f, by = 0.f, bz = 0.f, bw = 0.f;
            for (int k = 0; k < c8; k += 8) {
                uint4 r = *(const uint4*)(lp + k);        // 8 raw u16 idx
                float4 w0 = *(const float4*)(base + ((r.x & 0xFFFFu) * 48u + jb));
                float4 w1 = *(const float4*)(base + ((r.x >> 16)     * 48u + jb));
                float4 w2 = *(const float4*)(base + ((r.y & 0xFFFFu) * 48u + jb));
                float4 w3 = *(const float4*)(base + ((r.y >> 16)     * 48u + jb));
                float4 w4 = *(const float4*)(base + ((r.z & 0xFFFFu) * 48u + jb));
                float4 w5 = *(const float4*)(base + ((r.z >> 16)     * 48u + jb));
                float4 w6 = *(const float4*)(base + ((r.w & 0xFFFFu) * 48u + jb));
                float4 w7 = *(const float4*)(base + ((r.w >> 16)     * 48u + jb));
                ax += w0.x; ay += w0.y; az += w0.z; aw += w0.w;
                bx += w1.x; by += w1.y; bz += w1.z; bw += w1.w;
                ax += w2.x; ay += w2.y; az += w2.z; aw += w2.w;
                bx += w3.x; by += w3.y; bz += w3.z; bw += w3.w;
                ax += w4.x; ay += w4.y; az += w4.z; aw += w4.w;
                bx += w5.x; by += w5.y; bz += w5.z; bw += w5.w;
                ax += w6.x; ay += w6.y; az += w6.z; aw += w6.w;
                bx += w7.x; by += w7.y; bz += w7.z; bw += w7.w;
            }
            float4 r4;
            r4.x = ax + bx; r4.y = ay + by; r4.z = az + bz; r4.w = aw + bw;
            *(float4*)(z + (size_t)tb * D2 + j0 + ((threadIdx.x & 1) << 2)) = r4;
        }
    } else {
        // ---------------- global-role ----------------
        const int gbid  = blockIdx.x - 512;
        const int slice = gbid & 15;           // j-slice of 16 in [256,512)
        const int chunk = gbid >> 4;
        const int j0 = 256 + slice * 16;

        const int tbsub = threadIdx.x >> 2;                       // 0..63
        const char* gb = (const char*)Wtg + (size_t)(j0 << 2)
                       + ((threadIdx.x & 3) << 4);
        const int tb0 = chunk * (NTB / 16);
        const int tb1 = tb0 + (NTB / 16);

        for (int tb = tb0 + tbsub; tb < tb1; tb += 64) {
            const unsigned short* lp = lists + (size_t)tb * LIST_PAD;
            const int c8 = (int)cnt8s[tb];
            float ax = 0.f, ay = 0.f, az = 0.f, aw = 0.f;
            float bx = 0.f, by = 0.f, bz = 0.f, bw = 0.f;
            for (int k = 0; k < c8; k += 8) {
                uint4 r = *(const uint4*)(lp + k);
                float4 w0 = *(const float4*)(gb + ((size_t)(r.x & 0xFFFFu) << 11));
                float4 w1 = *(const float4*)(gb + ((size_t)(r.x >> 16)     << 11));
                float4 w2 = *(const float4*)(gb + ((size_t)(r.y & 0xFFFFu) << 11));
                float4 w3 = *(const float4*)(gb + ((size_t)(r.y >> 16)     << 11));
                float4 w4 = *(const float4*)(gb + ((size_t)(r.z & 0xFFFFu) << 11));
                float4 w5 = *(const float4*)(gb + ((size_t)(r.z >> 16)     << 11));
                float4 w6 = *(const float4*)(gb + ((size_t)(r.w & 0xFFFFu) << 11));
                float4 w7 = *(const float4*)(gb + ((size_t)(r.w >> 16)     << 11));
                ax += w0.x; ay += w0.y; az += w0.z; aw += w0.w;
                bx += w1.x; by += w1.y; bz += w1.z; bw += w1.w;
                ax += w2.x; ay += w2.y; az += w2.z; aw += w2.w;
                bx += w3.x; by += w3.y; bz += w3.z; bw += w3.w;
                ax += w4.x; ay += w4.y; az += w4.z; aw += w4.w;
                bx += w5.x; by += w5.y; bz += w5.z; bw += w5.w;
                ax += w6.x; ay += w6.y; az += w6.z; aw += w6.w;
                bx += w7.x; by += w7.y; bz += w7.z; bw += w7.w;
            }
            float4 r4;
            r4.x = ax + bx; r4.y = ay + by; r4.z = az + bz; r4.w = aw + bw;
            *(float4*)(z + (size_t)tb * D2 + j0 + ((threadIdx.x & 3) << 2)) = r4;
        }
    }
}

// elementwise LIF scan over t (HBM-bound)
__global__ __launch_bounds__(256) void lif_scan(
    const float* __restrict__ z, float* __restrict__ out)
{
    const int gid = blockIdx.x * 256 + threadIdx.x;   // b*D2 + j
    out[gid] = 0.f;                                   // step-0 row zeros
    float I = 0.f, V = 0.f;
    const float* zp = z + gid;
    float* op = out + (size_t)(BATCH * D2) + gid;
    for (int t0 = 0; t0 < NSTEP; t0 += 8) {
        const int n = (NSTEP - t0 < 8) ? (NSTEP - t0) : 8;
        float zz[8];
        #pragma unroll
        for (int u = 0; u < 8; ++u)
            if (u < n) zz[u] = zp[(size_t)(t0 + u) * (BATCH * D2)];
        #pragma unroll
        for (int u = 0; u < 8; ++u)
            if (u < n) {
                I = 0.8f * I + zz[u];
                float Vp = 0.95f * V + 0.05f * I;
                float s = (Vp > 1.0f) ? 1.0f : 0.f;
                V = (1.0f - s) * Vp;
                op[(size_t)(t0 + u) * (BATCH * D2)] = s;
            }
    }
}

// ======================= tier-2 kernels (R8 path) ============================
__global__ __launch_bounds__(256) void prep_lists(
    const float* __restrict__ x, unsigned short* __restrict__ lists,
    unsigned int* __restrict__ cnt4s)
{
    const int wid  = blockIdx.x * 4 + (threadIdx.x >> 6);
    const int lane = threadIdx.x & 63;
    const float* xt = x + (size_t)wid * D1;
    unsigned short* lp = lists + (size_t)wid * LIST_PAD;
    int cnt = 0;
    for (int base = 0; base < D1; base += 64) {
        int i = base + lane;
        bool a = (i < D1) && (xt[i] > 0.5f);
        unsigned long long m = __ballot(a);
        int pre = __popcll(m & ((1ull << lane) - 1ull));
        if (a) {
            int p = cnt + pre;
            if (p < LIST_PAD) lp[p] = (unsigned short)(i * ROWB);
        }
        cnt += __popcll(m);
    }
    if (cnt > LIST_PAD) cnt = LIST_PAD;
    int cnt4 = (cnt + 3) & ~3;
    if (lane < cnt4 - cnt) lp[cnt + lane] = (unsigned short)(D1 * ROWB);
    if (lane == 0) cnt4s[wid] = (unsigned int)cnt4;
}

__global__ __launch_bounds__(256, 4) void gather_lds(
    const float* __restrict__ W, const unsigned short* __restrict__ lists,
    const unsigned int* __restrict__ cnt4s, float* __restrict__ z)
{
    const int slice = blockIdx.x & 63;
    const int chunk = blockIdx.x >> 6;
    const int j0 = slice * 8;
    __shared__ __align__(16) float wt[D1P * (ROWB / 4)];
    for (int v = threadIdx.x; v < 8 * D1; v += 256) {
        int jj = v & 7;
        int i  = v >> 3;
        wt[i * (ROWB / 4) + jj] = W[(size_t)(j0 + jj) * D1 + i];
    }
    if (threadIdx.x < (ROWB / 4)) wt[D1 * (ROWB / 4) + threadIdx.x] = 0.f;
    __syncthreads();
    const int tbsub = threadIdx.x >> 1;
    const unsigned int jb = (unsigned int)((threadIdx.x & 1) << 4);
    const char* base = (const char*)wt;
    const int tb0 = chunk * (NTB / 16);
    const int tb1 = tb0 + (NTB / 16);
    for (int tb = tb0 + tbsub; tb < tb1; tb += 128) {
        const unsigned short* lp = lists + (size_t)tb * LIST_PAD;
        const int c4 = (int)cnt4s[tb];
        float ax = 0.f, ay = 0.f, az = 0.f, aw = 0.f;
        float bx = 0.f, by = 0.f, bz = 0.f, bw = 0.f;
        int k = 0;
        for (; k + 8 <= c4; k += 8) {
            uint4 r = *(const uint4*)(lp + k);
            float4 w0 = *(const float4*)(base + ((r.x & 0xFFFFu) + jb));
            float4 w1 = *(const float4*)(base + ((r.x >> 16)     + jb));
            float4 w2 = *(const float4*)(base + ((r.y & 0xFFFFu) + jb));
            float4 w3 = *(const float4*)(base + ((r.y >> 16)     + jb));
            float4 w4 = *(const float4*)(base + ((r.z & 0xFFFFu) + jb));
            float4 w5 = *(const float4*)(base + ((r.z >> 16)     + jb));
            float4 w6 = *(const float4*)(base + ((r.w & 0xFFFFu) + jb));
            float4 w7 = *(const float4*)(base + ((r.w >> 16)     + jb));
            ax += w0.x; ay += w0.y; az += w0.z; aw += w0.w;
            bx += w1.x; by += w1.y; bz += w1.z; bw += w1.w;
            ax += w2.x; ay += w2.y; az += w2.z; aw += w2.w;
            bx += w3.x; by += w3.y; bz += w3.z; bw += w3.w;
            ax += w4.x; ay += w4.y; az += w4.z; aw += w4.w;
            bx += w5.x; by += w5.y; bz += w5.z; bw += w5.w;
            ax += w6.x; ay += w6.y; az += w6.z; aw += w6.w;
            bx += w7.x; by += w7.y; bz += w7.z; bw += w7.w;
        }
        if (k < c4) {
            uint2 r = *(const uint2*)(lp + k);
            float4 w0 = *(const float4*)(base + ((r.x & 0xFFFFu) + jb));
            float4 w1 = *(const float4*)(base + ((r.x >> 16)     + jb));
            float4 w2 = *(const float4*)(base + ((r.y & 0xFFFFu) + jb));
            float4 w3 = *(const float4*)(base + ((r.y >> 16)     + jb));
            ax += w0.x; ay += w0.y; az += w0.z; aw += w0.w;
            bx += w1.x; by += w1.y; bz += w1.z; bw += w1.w;
            ax += w2.x; ay += w2.y; az += w2.z; aw += w2.w;
            bx += w3.x; by += w3.y; bz += w3.z; bw += w3.w;
        }
        float4 r4;
        r4.x = ax + bx; r4.y = ay + by; r4.z = az + bz; r4.w = aw + bw;
        *(float4*)(z + (size_t)tb * D2 + j0 + ((threadIdx.x & 1) << 2)) = r4;
    }
}

// ======================= tier-3 kernels (R6 path) ============================
__global__ void transpose_w(const float* __restrict__ W, float* __restrict__ Wt) {
    __shared__ float tile[32][33];
    int i0 = blockIdx.x * 32;
    int j0 = blockIdx.y * 32;
    int tx = threadIdx.x, ty = threadIdx.y;
    for (int r = 0; r < 32; r += 8) {
        int jj = j0 + ty + r, ii = i0 + tx;
        float v = 0.f;
        if (jj < D2 && ii < D1) v = W[jj * D1 + ii];
        tile[ty + r][tx] = v;
    }
    __syncthreads();
    for (int r = 0; r < 32; r += 8) {
        int ii = i0 + ty + r, jj = j0 + tx;
        if (ii < D1P && jj < D2) Wt[ii * D2 + jj] = tile[tx][ty + r];
    }
}

__global__ __launch_bounds__(512) void gather_z(
    const float* __restrict__ x, const float* __restrict__ Wt,
    float* __restrict__ z)
{
    const int g    = threadIdx.x >> 7;
    const int t128 = threadIdx.x & 127;
    const int half = (threadIdx.x >> 6) & 1;
    const int lane = threadIdx.x & 63;
    const int tb   = blockIdx.x * 4 + g;
    __shared__ __align__(16) unsigned int s_off[4][2][HCAP];
    __shared__ int s_cnt[4][2];
    {
        const float* xh = x + (size_t)tb * D1 + half * HALF1;
        unsigned int* lp = s_off[g][half];
        int cnt = 0;
        for (int base = 0; base < HALF1; base += 64) {
            int i = base + lane;
            bool a = (i < HALF1) && (xh[i] > 0.5f);
            unsigned long long m = __ballot(a);
            int pre = __popcll(m & ((1ull << lane) - 1ull));
            if (a) {
                int p = cnt + pre;
                if (p < HCAP) lp[p] = (unsigned int)((half * HALF1 + i) << 11);
            }
            cnt += __popcll(m);
        }
        if (cnt > HCAP) cnt = HCAP;
        int cnt4 = (cnt + 3) & ~3;
        if (lane < cnt4 - cnt) lp[cnt + lane] = (unsigned int)(D1 << 11);
        if (lane == 0) s_cnt[g][half] = cnt4;
    }
    __syncthreads();
    const char* wj = (const char*)Wt + (t128 << 4);
    float ax0 = 0.f, ay0 = 0.f, az0 = 0.f, aw0 = 0.f;
    float ax1 = 0.f, ay1 = 0.f, az1 = 0.f, aw1 = 0.f;
    #pragma unroll
    for (int h = 0; h < 2; ++h) {
        const unsigned int* l = s_off[g][h];
        const int c4 = s_cnt[g][h];
        for (int k = 0; k < c4; k += 4) {
            uint4 o = *(const uint4*)(l + k);
            float4 w0 = *(const float4*)(wj + o.x);
            float4 w1 = *(const float4*)(wj + o.y);
            float4 w2 = *(const float4*)(wj + o.z);
            float4 w3 = *(const float4*)(wj + o.w);
            ax0 += w0.x; ay0 += w0.y; az0 += w0.z; aw0 += w0.w;
            ax1 += w1.x; ay1 += w1.y; az1 += w1.z; aw1 += w1.w;
            ax0 += w2.x; ay0 += w2.y; az0 += w2.z; aw0 += w2.w;
            ax1 += w3.x; ay1 += w3.y; az1 += w3.z; aw1 += w3.w;
        }
    }
    float4 r;
    r.x = ax0 + ax1; r.y = ay0 + ay1; r.z = az0 + az1; r.w = aw0 + aw1;
    *(float4*)(z + (size_t)tb * D2 + (t128 << 2)) = r;
}

// ======================= tier-4: self-contained naive ========================
__global__ __launch_bounds__(256) void snn_fallback(
    const float* __restrict__ x, const float* __restrict__ Wfull,
    float* __restrict__ out)
{
    const int b = blockIdx.x >> 1;
    const int jhalf = blockIdx.x & 1;
    const int j = jhalf * 256 + threadIdx.x;
    const int lane = threadIdx.x & 63;
    __shared__ int s_cnt;
    __shared__ int s_list[D1];
    out[(size_t)b * D2 + j] = 0.f;
    float I = 0.f, V = 0.f;
    const float* wrow = Wfull + (size_t)j * D1;
    for (int t = 0; t < STEPS - 1; ++t) {
        if (threadIdx.x == 0) s_cnt = 0;
        __syncthreads();
        const float* xt = x + (size_t)(t * BATCH + b) * D1;
        for (int base = 0; base < D1; base += 256) {
            int i = base + threadIdx.x;
            bool active = (i < D1) && (xt[i] > 0.5f);
            unsigned long long mask = __ballot(active);
            int nact = __popcll(mask);
            int pre = __popcll(mask & ((1ull << lane) - 1ull));
            int wb = 0;
            if (lane == 0 && nact) wb = atomicAdd(&s_cnt, nact);
            wb = __shfl(wb, 0);
            if (active) s_list[wb + pre] = i;
        }
        __syncthreads();
        const int cnt = s_cnt;
        float a0 = 0.f, a1 = 0.f, a2 = 0.f, a3 = 0.f;
        int k = 0;
        for (; k + 4 <= cnt; k += 4) {
            a0 += wrow[s_list[k]];     a1 += wrow[s_list[k + 1]];
            a2 += wrow[s_list[k + 2]]; a3 += wrow[s_list[k + 3]];
        }
        for (; k < cnt; ++k) a0 += wrow[s_list[k]];
        float acc = (a0 + a1) + (a2 + a3);
        I = 0.8f * I + acc;
        float Vp = 0.95f * V + 0.05f * I;
        float s = (Vp > 1.0f) ? 1.0f : 0.f;
        V = (1.0f - s) * Vp;
        out[(size_t)(t + 1) * (BATCH * D2) + (size_t)b * D2 + j] = s;
        __syncthreads();
    }
}

extern "C" void kernel_launch(void* const* d_in, const int* in_sizes, int n_in,
                              void* d_out, int out_size, void* d_ws, size_t ws_size,
                              hipStream_t stream) {
    const float* x = (const float*)d_in[0];   // [100][256][784]
    const float* w = (const float*)d_in[1];   // [512][784]
    float* out = (float*)d_out;               // [100][256][512]
    char* ws = (char*)d_ws;

    if (ws_size >= WS_T1) {
        float* wt = (float*)ws;
        unsigned short* lists = (unsigned short*)(ws + H_LISTS_OFF);
        unsigned int* cnt8s = (unsigned int*)(ws + H_CNTS_OFF);
        float* z = (float*)(ws + H_Z_OFF);
        prep_fused<<<NBLK_T + NTB / 4, 256, 0, stream>>>(w, x, wt, lists, cnt8s);
        gather_hybrid<<<768, 256, 0, stream>>>(wt, lists, cnt8s, z);
        lif_scan<<<BATCH * D2 / 256, 256, 0, stream>>>(z, out);
    } else if (ws_size >= WS_T2) {
        unsigned short* lists = (unsigned short*)(ws + L2_LISTS_OFF);
        unsigned int* cnt4s = (unsigned int*)(ws + L2_CNTS_OFF);
        float* z = (float*)(ws + L2_Z_OFF);
        prep_lists<<<NTB / 4, 256, 0, stream>>>(x, lists, cnt4s);
        gather_lds<<<1024, 256, 0, stream>>>(w, lists, cnt4s, z);
        lif_scan<<<BATCH * D2 / 256, 256, 0, stream>>>(z, out);
    } else if (ws_size >= WS_T3) {
        float* wt = (float*)ws;
        float* z  = (float*)(ws + T3_Z_OFF);
        dim3 tg(25, 16), tb(32, 8);
        transpose_w<<<tg, tb, 0, stream>>>(w, wt);
        gather_z<<<NTB / 4, 512, 0, stream>>>(x, wt, z);
        lif_scan<<<BATCH * D2 / 256, 256, 0, stream>>>(z, out);
    } else {
        snn_fallback<<<BATCH * 2, 256, 0, stream>>>(x, w, out);
    }
}

// Round 10
// 227.444 us; speedup vs baseline: 1.2149x; 1.2149x over previous
//
#include <hip/hip_runtime.h>

#define STEPS 100
#define BATCH 256
#define D1 784
#define D1P 785            // +1 zero row = padding target for gathers
#define D2 512
#define NSTEP 99           // computed steps t = 0..98 (output rows 1..99)
#define NTB (NSTEP * BATCH)        // 25344
#define LIST_PAD 80        // u16 entries per (t,b); max spikes ~66 (verified R3+)
#define ROWB 48            // LDS row stride in bytes (12 floats; 8 bank classes)

// ---- tier-1 (R8 pure-LDS) ws layout: lists u16(i*48) ++ cnt8 ++ z ----
#define L1_LISTS_OFF 0
#define L1_LISTS_BYTES ((size_t)NTB * LIST_PAD * 2)          // 4,055,040
#define L1_CNTS_OFF  L1_LISTS_BYTES
#define L1_CNTS_BYTES ((size_t)NTB * 4)
#define L1_Z_OFF     (((L1_CNTS_OFF + L1_CNTS_BYTES) + 255) & ~(size_t)255)
#define Z_BYTES      ((size_t)NTB * D2 * 4)                  // 51,904,512
#define WS_T1        (L1_Z_OFF + Z_BYTES)                    // ~56.1 MB

// ---- tier-2 (R6) ws layout: Wt fp32 ++ z ----
#define WT_BYTES  (D1P * D2 * 4)
#define T2_Z_OFF  ((size_t)((WT_BYTES + 255) & ~255))
#define WS_T2     (T2_Z_OFF + Z_BYTES)                       // ~53.5 MB

#define HALF1 392
#define HCAP  64

// ======================= tier-1 kernels ======================================

// prep: one wave per (t,b); emit u16 PRE-SHIFTED byte offsets (i*48 = LDS row
// offset), padded with the zero row (784*48) to a multiple of 8, minimum 8.
__global__ __launch_bounds__(256) void prep_lists(
    const float* __restrict__ x, unsigned short* __restrict__ lists,
    unsigned int* __restrict__ cnt8s)
{
    const int wid  = blockIdx.x * 4 + (threadIdx.x >> 6);   // t*BATCH + b
    const int lane = threadIdx.x & 63;
    const float* xt = x + (size_t)wid * D1;
    unsigned short* lp = lists + (size_t)wid * LIST_PAD;

    int cnt = 0;
    for (int base = 0; base < D1; base += 64) {
        int i = base + lane;
        bool a = (i < D1) && (xt[i] > 0.5f);
        unsigned long long m = __ballot(a);
        int pre = __popcll(m & ((1ull << lane) - 1ull));
        if (a) {
            int p = cnt + pre;
            if (p < LIST_PAD) lp[p] = (unsigned short)(i * ROWB);
        }
        cnt += __popcll(m);
    }
    if (cnt > LIST_PAD) cnt = LIST_PAD;
    int cnt8 = (cnt + 7) & ~7;
    if (cnt8 < 8) cnt8 = 8;                               // guarantee >= 1 chunk
    if (lane < cnt8 - cnt) lp[cnt + lane] = (unsigned short)(D1 * ROWB);
    if (lane == 0) cnt8s[wid] = (unsigned int)cnt8;
}

// gather from LDS-staged 8-column W slice, with next-chunk list prefetch.
// 1024 blocks = 64 j-slices x 16 tb-chunks = exactly 4 blocks/CU.
__global__ __launch_bounds__(256, 4) void gather_lds(
    const float* __restrict__ W,             // [D2][D1] original layout
    const unsigned short* __restrict__ lists,
    const unsigned int* __restrict__ cnt8s,  // multiples of 8, >= 8
    float* __restrict__ z)                   // [NSTEP][BATCH][D2]
{
    const int slice = blockIdx.x & 63;       // j-slice of 8
    const int chunk = blockIdx.x >> 6;       // tb-chunk of 1584
    const int j0 = slice * 8;

    __shared__ __align__(16) float wt[D1P * (ROWB / 4)];   // 37,680 B

    // stage: wt[i*12 + jj] = W[j0+jj][i]
    for (int v = threadIdx.x; v < 8 * D1; v += 256) {
        int jj = v & 7;
        int i  = v >> 3;
        wt[i * (ROWB / 4) + jj] = W[(size_t)(j0 + jj) * D1 + i];
    }
    if (threadIdx.x < (ROWB / 4)) wt[D1 * (ROWB / 4) + threadIdx.x] = 0.f;
    __syncthreads();

    const int tbsub = threadIdx.x >> 1;                     // 0..127
    const unsigned int jb = (unsigned int)((threadIdx.x & 1) << 4); // 0 / 16 B
    const char* base = (const char*)wt;
    const int tb0 = chunk * (NTB / 16);
    const int tb1 = tb0 + (NTB / 16);

    for (int tb = tb0 + tbsub; tb < tb1; tb += 128) {
        const unsigned short* lp = lists + (size_t)tb * LIST_PAD;
        const int c8 = (int)cnt8s[tb];                      // >= 8, mult of 8
        uint4 r = *(const uint4*)lp;                        // first chunk
        float ax = 0.f, ay = 0.f, az = 0.f, aw = 0.f;
        float bx = 0.f, by = 0.f, bz = 0.f, bw = 0.f;
        for (int k = 0; k < c8; k += 8) {
            int kn = k + 8;                                 // prefetch index,
            if (kn > c8 - 8) kn = c8 - 8;                   // clamped (c8>=8)
            uint4 rn = *(const uint4*)(lp + kn);            // issued pre-gather
            float4 w0 = *(const float4*)(base + ((r.x & 0xFFFFu) + jb));
            float4 w1 = *(const float4*)(base + ((r.x >> 16)     + jb));
            float4 w2 = *(const float4*)(base + ((r.y & 0xFFFFu) + jb));
            float4 w3 = *(const float4*)(base + ((r.y >> 16)     + jb));
            float4 w4 = *(const float4*)(base + ((r.z & 0xFFFFu) + jb));
            float4 w5 = *(const float4*)(base + ((r.z >> 16)     + jb));
            float4 w6 = *(const float4*)(base + ((r.w & 0xFFFFu) + jb));
            float4 w7 = *(const float4*)(base + ((r.w >> 16)     + jb));
            ax += w0.x; ay += w0.y; az += w0.z; aw += w0.w;
            bx += w1.x; by += w1.y; bz += w1.z; bw += w1.w;
            ax += w2.x; ay += w2.y; az += w2.z; aw += w2.w;
            bx += w3.x; by += w3.y; bz += w3.z; bw += w3.w;
            ax += w4.x; ay += w4.y; az += w4.z; aw += w4.w;
            bx += w5.x; by += w5.y; bz += w5.z; bw += w5.w;
            ax += w6.x; ay += w6.y; az += w6.z; aw += w6.w;
            bx += w7.x; by += w7.y; bz += w7.z; bw += w7.w;
            r = rn;
        }
        float4 r4;
        r4.x = ax + bx; r4.y = ay + by; r4.z = az + bz; r4.w = aw + bw;
        *(float4*)(z + (size_t)tb * D2 + j0 + ((threadIdx.x & 1) << 2)) = r4;
    }
}

// elementwise LIF scan over t (HBM-bound)
__global__ __launch_bounds__(256) void lif_scan(
    const float* __restrict__ z, float* __restrict__ out)
{
    const int gid = blockIdx.x * 256 + threadIdx.x;   // b*D2 + j
    out[gid] = 0.f;                                   // step-0 row zeros
    float I = 0.f, V = 0.f;
    const float* zp = z + gid;
    float* op = out + (size_t)(BATCH * D2) + gid;
    for (int t0 = 0; t0 < NSTEP; t0 += 8) {
        const int n = (NSTEP - t0 < 8) ? (NSTEP - t0) : 8;
        float zz[8];
        #pragma unroll
        for (int u = 0; u < 8; ++u)
            if (u < n) zz[u] = zp[(size_t)(t0 + u) * (BATCH * D2)];
        #pragma unroll
        for (int u = 0; u < 8; ++u)
            if (u < n) {
                I = 0.8f * I + zz[u];
                float Vp = 0.95f * V + 0.05f * I;
                float s = (Vp > 1.0f) ? 1.0f : 0.f;
                V = (1.0f - s) * Vp;
                op[(size_t)(t0 + u) * (BATCH * D2)] = s;
            }
    }
}

// ======================= tier-2 kernels (R6 path) ============================
__global__ void transpose_w(const float* __restrict__ W, float* __restrict__ Wt) {
    __shared__ float tile[32][33];
    int i0 = blockIdx.x * 32;
    int j0 = blockIdx.y * 32;
    int tx = threadIdx.x, ty = threadIdx.y;
    for (int r = 0; r < 32; r += 8) {
        int jj = j0 + ty + r, ii = i0 + tx;
        float v = 0.f;
        if (jj < D2 && ii < D1) v = W[jj * D1 + ii];
        tile[ty + r][tx] = v;
    }
    __syncthreads();
    for (int r = 0; r < 32; r += 8) {
        int ii = i0 + ty + r, jj = j0 + tx;
        if (ii < D1P && jj < D2) Wt[ii * D2 + jj] = tile[tx][ty + r];
    }
}

__global__ __launch_bounds__(512) void gather_z(
    const float* __restrict__ x, const float* __restrict__ Wt,
    float* __restrict__ z)
{
    const int g    = threadIdx.x >> 7;
    const int t128 = threadIdx.x & 127;
    const int half = (threadIdx.x >> 6) & 1;
    const int lane = threadIdx.x & 63;
    const int tb   = blockIdx.x * 4 + g;
    __shared__ __align__(16) unsigned int s_off[4][2][HCAP];
    __shared__ int s_cnt[4][2];
    {
        const float* xh = x + (size_t)tb * D1 + half * HALF1;
        unsigned int* lp = s_off[g][half];
        int cnt = 0;
        for (int base = 0; base < HALF1; base += 64) {
            int i = base + lane;
            bool a = (i < HALF1) && (xh[i] > 0.5f);
            unsigned long long m = __ballot(a);
            int pre = __popcll(m & ((1ull << lane) - 1ull));
            if (a) {
                int p = cnt + pre;
                if (p < HCAP) lp[p] = (unsigned int)((half * HALF1 + i) << 11);
            }
            cnt += __popcll(m);
        }
        if (cnt > HCAP) cnt = HCAP;
        int cnt4 = (cnt + 3) & ~3;
        if (lane < cnt4 - cnt) lp[cnt + lane] = (unsigned int)(D1 << 11);
        if (lane == 0) s_cnt[g][half] = cnt4;
    }
    __syncthreads();
    const char* wj = (const char*)Wt + (t128 << 4);
    float ax0 = 0.f, ay0 = 0.f, az0 = 0.f, aw0 = 0.f;
    float ax1 = 0.f, ay1 = 0.f, az1 = 0.f, aw1 = 0.f;
    #pragma unroll
    for (int h = 0; h < 2; ++h) {
        const unsigned int* l = s_off[g][h];
        const int c4 = s_cnt[g][h];
        for (int k = 0; k < c4; k += 4) {
            uint4 o = *(const uint4*)(l + k);
            float4 w0 = *(const float4*)(wj + o.x);
            float4 w1 = *(const float4*)(wj + o.y);
            float4 w2 = *(const float4*)(wj + o.z);
            float4 w3 = *(const float4*)(wj + o.w);
            ax0 += w0.x; ay0 += w0.y; az0 += w0.z; aw0 += w0.w;
            ax1 += w1.x; ay1 += w1.y; az1 += w1.z; aw1 += w1.w;
            ax0 += w2.x; ay0 += w2.y; az0 += w2.z; aw0 += w2.w;
            ax1 += w3.x; ay1 += w3.y; az1 += w3.z; aw1 += w3.w;
        }
    }
    float4 r;
    r.x = ax0 + ax1; r.y = ay0 + ay1; r.z = az0 + az1; r.w = aw0 + aw1;
    *(float4*)(z + (size_t)tb * D2 + (t128 << 2)) = r;
}

// ======================= tier-3: self-contained naive ========================
__global__ __launch_bounds__(256) void snn_fallback(
    const float* __restrict__ x, const float* __restrict__ Wfull,
    float* __restrict__ out)
{
    const int b = blockIdx.x >> 1;
    const int jhalf = blockIdx.x & 1;
    const int j = jhalf * 256 + threadIdx.x;
    const int lane = threadIdx.x & 63;
    __shared__ int s_cnt;
    __shared__ int s_list[D1];
    out[(size_t)b * D2 + j] = 0.f;
    float I = 0.f, V = 0.f;
    const float* wrow = Wfull + (size_t)j * D1;
    for (int t = 0; t < STEPS - 1; ++t) {
        if (threadIdx.x == 0) s_cnt = 0;
        __syncthreads();
        const float* xt = x + (size_t)(t * BATCH + b) * D1;
        for (int base = 0; base < D1; base += 256) {
            int i = base + threadIdx.x;
            bool active = (i < D1) && (xt[i] > 0.5f);
            unsigned long long mask = __ballot(active);
            int nact = __popcll(mask);
            int pre = __popcll(mask & ((1ull << lane) - 1ull));
            int wb = 0;
            if (lane == 0 && nact) wb = atomicAdd(&s_cnt, nact);
            wb = __shfl(wb, 0);
            if (active) s_list[wb + pre] = i;
        }
        __syncthreads();
        const int cnt = s_cnt;
        float a0 = 0.f, a1 = 0.f, a2 = 0.f, a3 = 0.f;
        int k = 0;
        for (; k + 4 <= cnt; k += 4) {
            a0 += wrow[s_list[k]];     a1 += wrow[s_list[k + 1]];
            a2 += wrow[s_list[k + 2]]; a3 += wrow[s_list[k + 3]];
        }
        for (; k < cnt; ++k) a0 += wrow[s_list[k]];
        float acc = (a0 + a1) + (a2 + a3);
        I = 0.8f * I + acc;
        float Vp = 0.95f * V + 0.05f * I;
        float s = (Vp > 1.0f) ? 1.0f : 0.f;
        V = (1.0f - s) * Vp;
        out[(size_t)(t + 1) * (BATCH * D2) + (size_t)b * D2 + j] = s;
        __syncthreads();
    }
}

extern "C" void kernel_launch(void* const* d_in, const int* in_sizes, int n_in,
                              void* d_out, int out_size, void* d_ws, size_t ws_size,
                              hipStream_t stream) {
    const float* x = (const float*)d_in[0];   // [100][256][784]
    const float* w = (const float*)d_in[1];   // [512][784]
    float* out = (float*)d_out;               // [100][256][512]
    char* ws = (char*)d_ws;

    if (ws_size >= WS_T1) {
        unsigned short* lists = (unsigned short*)(ws + L1_LISTS_OFF);
        unsigned int* cnt8s = (unsigned int*)(ws + L1_CNTS_OFF);
        float* z = (float*)(ws + L1_Z_OFF);
        prep_lists<<<NTB / 4, 256, 0, stream>>>(x, lists, cnt8s);
        gather_lds<<<1024, 256, 0, stream>>>(w, lists, cnt8s, z);
        lif_scan<<<BATCH * D2 / 256, 256, 0, stream>>>(z, out);
    } else if (ws_size >= WS_T2) {
        float* wt = (float*)ws;
        float* z  = (float*)(ws + T2_Z_OFF);
        dim3 tg(25, 16), tb(32, 8);
        transpose_w<<<tg, tb, 0, stream>>>(w, wt);
        gather_z<<<NTB / 4, 512, 0, stream>>>(x, wt, z);
        lif_scan<<<BATCH * D2 / 256, 256, 0, stream>>>(z, out);
    } else {
        snn_fallback<<<BATCH * 2, 256, 0, stream>>>(x, w, out);
    }
}